// Round 1
// baseline (309.893 us; speedup 1.0000x reference)
//
#include <hip/hip_runtime.h>
#include <cmath>

#define DEVFN __device__ __forceinline__

// Problem constants
constexpr int NB = 4;        // batch
constexpr int TT = 2048;     // sequence
constexpr int CD = 1024;     // channels (= H*HS)
constexpr int MROWS = NB * TT;   // 8192
constexpr int NCH = 128;     // scan chunks over T
constexpr int CHL = TT / NCH;    // 16 steps per chunk

// ---------------- bf16 bit helpers (RNE) ----------------
DEVFN float bf2f(unsigned short u) {
    union { unsigned int i; float f; } z; z.i = ((unsigned int)u) << 16; return z.f;
}
DEVFN unsigned short f2bf(float f) {
    union { float f; unsigned int i; } z; z.f = f;
    unsigned int r = z.i + 0x7FFFu + ((z.i >> 16) & 1u);
    return (unsigned short)(r >> 16);
}

union F4 { float4 v; float a[4]; };

// ---------------- cast fp32 -> bf16 bits ----------------
__global__ __launch_bounds__(256) void cast_bf16_kernel(const float* __restrict__ src,
                                                        unsigned short* __restrict__ dst, int n4) {
    int i = blockIdx.x * 256 + threadIdx.x;
    if (i >= n4) return;
    float4 v = ((const float4*)src)[i];
    ushort4 o;
    o.x = f2bf(v.x); o.y = f2bf(v.y); o.z = f2bf(v.z); o.w = f2bf(v.w);
    ((ushort4*)dst)[i] = o;
}

// ---------------- time interp: out[t] = eps*x[t-1] + (1-eps)*x[t+1] (zero pad) ----------------
__global__ __launch_bounds__(256) void interp_kernel(const float* __restrict__ x,
                                                     unsigned short* __restrict__ dst, float eps) {
    int idx = blockIdx.x * 256 + threadIdx.x;      // one float4 per thread
    int e = idx * 4;
    int t = (e / CD) % TT;
    float4 a = make_float4(0.f, 0.f, 0.f, 0.f);
    float4 b = make_float4(0.f, 0.f, 0.f, 0.f);
    if (t > 0)      a = *(const float4*)(x + e - CD);
    if (t < TT - 1) b = *(const float4*)(x + e + CD);
    float om = 1.0f - eps;
    ushort4 o;
    o.x = f2bf(eps * a.x + om * b.x);
    o.y = f2bf(eps * a.y + om * b.y);
    o.z = f2bf(eps * a.z + om * b.z);
    o.w = f2bf(eps * a.w + om * b.w);
    *(ushort4*)(dst + e) = o;
}

// ---------------- bf16 MFMA GEMM:  C[M,N] = A[M,K] @ B[N,K]^T + bias  (m97 recipe) ----------------
typedef __attribute__((ext_vector_type(8))) short short8;   // 8 bf16 (4 VGPRs)
typedef __attribute__((ext_vector_type(4))) float f32x4;

#define BM 128
#define BN 128
#define BK 64

DEVFN void store_val(float* p, float v) { *p = v; }
DEVFN void store_val(unsigned short* p, float v) { *p = f2bf(v); }

typedef const __attribute__((address_space(1))) void* gas_ptr;
typedef __attribute__((address_space(3))) void* las_ptr;

DEVFN void async_copy16(const void* g, void* l) {
    __builtin_amdgcn_global_load_lds((gas_ptr)g, (las_ptr)l, 16, 0, 0);
}

template <typename OutT>
__global__ __launch_bounds__(256) void gemm_bt(const unsigned short* __restrict__ A,   // M x K bf16 bits
                                               const unsigned short* __restrict__ B,   // N x K bf16 bits
                                               const float* __restrict__ bias,         // N
                                               OutT* __restrict__ C,                   // M x N
                                               int M, int N, int K) {
    __shared__ __align__(16) unsigned short As[BM][BK];
    __shared__ __align__(16) unsigned short Bs[BN][BK];

    const int tid  = threadIdx.x;
    const int wave = tid >> 6;
    const int lane = tid & 63;

    const int tile_m = blockIdx.x * BM;
    const int tile_n = blockIdx.y * BN;

    const int st_row = lane >> 3;          // 0..7 within 8-row chunk
    const int st_k   = (lane & 7) * 8;     // element offset in K

    const int wr = wave >> 1;              // 0..1
    const int wc = wave & 1;               // 0..1
    const int lane_lo = lane & 15;
    const int lane_hi = lane >> 4;         // 0..3

    f32x4 acc[4][4];
#pragma unroll
    for (int i = 0; i < 4; i++)
#pragma unroll
        for (int j = 0; j < 4; j++) acc[i][j] = (f32x4)(0.f);

    for (int k0 = 0; k0 < K; k0 += BK) {
#pragma unroll
        for (int j = 0; j < 4; ++j) {
            int rbase = (j * 4 + wave) * 8;
            const unsigned short* gA = A + (size_t)(tile_m + rbase + st_row) * K + k0 + st_k;
            async_copy16(gA, &As[rbase][0]);
            const unsigned short* gB = B + (size_t)(tile_n + rbase + st_row) * K + k0 + st_k;
            async_copy16(gB, &Bs[rbase][0]);
        }
        __syncthreads();
#pragma unroll
        for (int ks = 0; ks < 2; ++ks) {
            short8 af[4], bf[4];
#pragma unroll
            for (int i = 0; i < 4; i++) {
                int row = wr * 64 + i * 16 + lane_lo;
                af[i] = *(const short8*)&As[row][ks * 32 + lane_hi * 8];
            }
#pragma unroll
            for (int i = 0; i < 4; i++) {
                int row = wc * 64 + i * 16 + lane_lo;
                bf[i] = *(const short8*)&Bs[row][ks * 32 + lane_hi * 8];
            }
#pragma unroll
            for (int i = 0; i < 4; i++)
#pragma unroll
                for (int j = 0; j < 4; j++)
                    acc[i][j] = __builtin_amdgcn_mfma_f32_16x16x32_bf16(af[i], bf[j], acc[i][j], 0, 0, 0);
        }
        __syncthreads();
    }

    // epilogue: C/D layout col = lane&15, row = (lane>>4)*4 + r  (verified m89/m91)
#pragma unroll
    for (int i = 0; i < 4; i++) {
#pragma unroll
        for (int j = 0; j < 4; j++) {
            int col = tile_n + wc * 64 + j * 16 + lane_lo;
            float bv = bias[col];
            int row0 = tile_m + wr * 64 + i * 16 + lane_hi * 4;
#pragma unroll
            for (int r = 0; r < 4; r++) {
                store_val(&C[(size_t)(row0 + r) * N + col], acc[i][j][r] + bv);
            }
        }
    }
}

// ---------------- scan kernels (chunked prefix sum of e and e*V) ----------------
DEVFN float clip_exp(float x) { return expf(fminf(fmaxf(x, -20.f), 10.f)); }

__global__ __launch_bounds__(256) void scan_partial_kernel(const float* __restrict__ Kb,
                                                           const float* __restrict__ Vb,
                                                           const float* __restrict__ td,
                                                           float* __restrict__ pE,
                                                           float* __restrict__ pEV) {
    int b = blockIdx.x;
    int n = b / NCH, ch = b % NCH;
    int c = threadIdx.x * 4;
    F4 w; w.v = *(const float4*)(td + c);
#pragma unroll
    for (int j = 0; j < 4; j++) w.a[j] = fmaxf(w.a[j], 0.f);
    float sE[4] = {0, 0, 0, 0}, sEV[4] = {0, 0, 0, 0};
    int t0 = ch * CHL;
    size_t base = ((size_t)n * TT + t0) * CD + c;
#pragma unroll 4
    for (int i = 0; i < CHL; ++i) {
        F4 k4, v4;
        k4.v = *(const float4*)(Kb + base + (size_t)i * CD);
        v4.v = *(const float4*)(Vb + base + (size_t)i * CD);
        float trem = (float)(TT - 1 - (t0 + i));
#pragma unroll
        for (int j = 0; j < 4; j++) {
            float e = clip_exp(-w.a[j] * trem + k4.a[j]);
            sE[j] += e;
            sEV[j] += e * v4.a[j];
        }
    }
    size_t pbase = ((size_t)n * NCH + ch) * CD + c;
    F4 oE, oEV;
#pragma unroll
    for (int j = 0; j < 4; j++) { oE.a[j] = sE[j]; oEV.a[j] = sEV[j]; }
    *(float4*)(pE + pbase) = oE.v;
    *(float4*)(pEV + pbase) = oEV.v;
}

__global__ __launch_bounds__(256) void scan_carry_kernel(float* __restrict__ pE,
                                                         float* __restrict__ pEV) {
    int idx = blockIdx.x * 256 + threadIdx.x;   // 0..4095 (n*CD + c)
    int n = idx / CD, c = idx % CD;
    float rE = 0.f, rEV = 0.f;
    for (int ch = 0; ch < NCH; ++ch) {
        size_t p = ((size_t)n * NCH + ch) * CD + c;
        float tE = pE[p];  pE[p]  = rE;  rE  += tE;
        float tV = pEV[p]; pEV[p] = rEV; rEV += tV;
    }
}

__global__ __launch_bounds__(256) void scan_apply_kernel(const float* __restrict__ Kb,
                                                         const float* __restrict__ Vb,
                                                         const unsigned short* __restrict__ Rb,
                                                         const float* __restrict__ td,
                                                         const float* __restrict__ Ub,
                                                         const float* __restrict__ pE,
                                                         const float* __restrict__ pEV,
                                                         unsigned short* __restrict__ gated) {
    int b = blockIdx.x;
    int n = b / NCH, ch = b % NCH;
    int c = threadIdx.x * 4;
    F4 w; w.v = *(const float4*)(td + c);
#pragma unroll
    for (int j = 0; j < 4; j++) w.a[j] = fmaxf(w.a[j], 0.f);
    F4 u; u.v = *(const float4*)(Ub + c);
    size_t pbase = ((size_t)n * NCH + ch) * CD + c;
    F4 cE, cEV;
    cE.v  = *(const float4*)(pE + pbase);
    cEV.v = *(const float4*)(pEV + pbase);
    int t0 = ch * CHL;
    size_t base = ((size_t)n * TT + t0) * CD + c;
#pragma unroll 4
    for (int i = 0; i < CHL; ++i) {
        F4 k4, v4;
        k4.v = *(const float4*)(Kb + base + (size_t)i * CD);
        v4.v = *(const float4*)(Vb + base + (size_t)i * CD);
        ushort4 ru = *(const ushort4*)(Rb + base + (size_t)i * CD);
        float r4[4] = { bf2f(ru.x), bf2f(ru.y), bf2f(ru.z), bf2f(ru.w) };
        float trem = (float)(TT - 1 - (t0 + i));
        ushort4 og;
        unsigned short* ogp = (unsigned short*)&og;
#pragma unroll
        for (int j = 0; j < 4; j++) {
            float e  = clip_exp(-w.a[j] * trem + k4.a[j]);
            float eu = clip_exp(u.a[j] + k4.a[j]);
            float Aj = cEV.a[j] + eu * v4.a[j];
            float Bj = cE.a[j] + eu;
            float wkv = Aj / Bj;
            float sig = 1.f / (1.f + expf(-r4[j]));
            ogp[j] = f2bf(sig * wkv);
            cEV.a[j] += e * v4.a[j];
            cE.a[j]  += e;
        }
        *(ushort4*)(gated + base + (size_t)i * CD) = og;
    }
}

// ---------------- launcher ----------------
extern "C" void kernel_launch(void* const* d_in, const int* in_sizes, int n_in,
                              void* d_out, int out_size, void* d_ws, size_t ws_size,
                              hipStream_t stream) {
    const float* x  = (const float*)d_in[0];
    const float* Wr = (const float*)d_in[1];
    const float* br = (const float*)d_in[2];
    const float* Wk = (const float*)d_in[3];
    const float* bk = (const float*)d_in[4];
    const float* Wv = (const float*)d_in[5];
    const float* bv = (const float*)d_in[6];
    const float* Wo = (const float*)d_in[7];
    const float* bo = (const float*)d_in[8];
    const float* td = (const float*)d_in[9];
    const float* U  = (const float*)d_in[10];
    float* out = (float*)d_out;

    // eps constants (host-side, double precision like the reference)
    const double eps0 = std::exp(-1.0 / 12.0);
    const float epsR = (float)(eps0 / 2.0);
    const float epsK = (float)(eps0 + 0.3 * 1.0 / 11.0);
    const float epsV = (float)eps0;

    // workspace carve-up (~108 MB total)
    char* p = (char*)d_ws;
    auto take = [&](size_t bytes) { char* q = p; p += (bytes + 255) & ~(size_t)255; return q; };
    unsigned short* Wr_bf = (unsigned short*)take((size_t)CD * CD * 2);
    unsigned short* Wk_bf = (unsigned short*)take((size_t)CD * CD * 2);
    unsigned short* Wv_bf = (unsigned short*)take((size_t)CD * CD * 2);
    unsigned short* Wo_bf = (unsigned short*)take((size_t)CD * CD * 2);
    unsigned short* xbuf  = (unsigned short*)take((size_t)MROWS * CD * 2);  // reused: xr/xk/xv, then gated
    float*          Kbuf  = (float*)take((size_t)MROWS * CD * 4);
    float*          Vbuf  = (float*)take((size_t)MROWS * CD * 4);
    unsigned short* Rbuf  = (unsigned short*)take((size_t)MROWS * CD * 2);
    float*          pE    = (float*)take((size_t)NB * NCH * CD * 4);
    float*          pEV   = (float*)take((size_t)NB * NCH * CD * 4);

    const int wn4 = CD * CD / 4;           // 262144
    cast_bf16_kernel<<<wn4 / 256, 256, 0, stream>>>(Wr, Wr_bf, wn4);
    cast_bf16_kernel<<<wn4 / 256, 256, 0, stream>>>(Wk, Wk_bf, wn4);
    cast_bf16_kernel<<<wn4 / 256, 256, 0, stream>>>(Wv, Wv_bf, wn4);
    cast_bf16_kernel<<<wn4 / 256, 256, 0, stream>>>(Wo, Wo_bf, wn4);

    const int in4 = MROWS * CD / 4;        // 2097152
    dim3 ggrid(MROWS / BM, CD / BN);       // 64 x 8

    interp_kernel<<<in4 / 256, 256, 0, stream>>>(x, xbuf, epsR);
    gemm_bt<unsigned short><<<ggrid, 256, 0, stream>>>(xbuf, Wr_bf, br, Rbuf, MROWS, CD, CD);
    interp_kernel<<<in4 / 256, 256, 0, stream>>>(x, xbuf, epsK);
    gemm_bt<float><<<ggrid, 256, 0, stream>>>(xbuf, Wk_bf, bk, Kbuf, MROWS, CD, CD);
    interp_kernel<<<in4 / 256, 256, 0, stream>>>(x, xbuf, epsV);
    gemm_bt<float><<<ggrid, 256, 0, stream>>>(xbuf, Wv_bf, bv, Vbuf, MROWS, CD, CD);

    scan_partial_kernel<<<NB * NCH, 256, 0, stream>>>(Kbuf, Vbuf, td, pE, pEV);
    scan_carry_kernel<<<(NB * CD) / 256, 256, 0, stream>>>(pE, pEV);
    scan_apply_kernel<<<NB * NCH, 256, 0, stream>>>(Kbuf, Vbuf, Rbuf, td, U, pE, pEV, xbuf);

    gemm_bt<float><<<ggrid, 256, 0, stream>>>(xbuf, Wo_bf, bo, out, MROWS, CD, CD);
}

// Round 2
// 274.778 us; speedup vs baseline: 1.1278x; 1.1278x over previous
//
#include <hip/hip_runtime.h>
#include <cmath>

#define DEVFN __device__ __forceinline__

// Problem constants
constexpr int NB = 4;        // batch
constexpr int TT = 2048;     // sequence
constexpr int CD = 1024;     // channels (= H*HS)
constexpr int MROWS = NB * TT;   // 8192
constexpr int NPROJ = 3 * CD;    // fused R/K/V projection width = 3072
constexpr int NCH = 128;     // scan chunks over T
constexpr int CHL = TT / NCH;    // 16 steps per chunk

// ---------------- bf16 bit helpers (RNE) ----------------
DEVFN float bf2f(unsigned short u) {
    union { unsigned int i; float f; } z; z.i = ((unsigned int)u) << 16; return z.f;
}
DEVFN unsigned short f2bf(float f) {
    union { float f; unsigned int i; } z; z.f = f;
    unsigned int r = z.i + 0x7FFFu + ((z.i >> 16) & 1u);
    return (unsigned short)(r >> 16);
}

union F4 { float4 v; float a[4]; };

// ---------------- cast fp32 -> bf16 bits ----------------
__global__ __launch_bounds__(256) void cast_bf16_kernel(const float* __restrict__ src,
                                                        unsigned short* __restrict__ dst, int n4) {
    int i = blockIdx.x * 256 + threadIdx.x;
    if (i >= n4) return;
    float4 v = ((const float4*)src)[i];
    ushort4 o;
    o.x = f2bf(v.x); o.y = f2bf(v.y); o.z = f2bf(v.z); o.w = f2bf(v.w);
    ((ushort4*)dst)[i] = o;
}

// ---------------- bf16 MFMA GEMM:  C[M,N] = A[M,K] @ B[N,K]^T (+ bias)  (m97 recipe) ----------------
typedef __attribute__((ext_vector_type(8))) short short8;   // 8 bf16 (4 VGPRs)
typedef __attribute__((ext_vector_type(4))) float f32x4;

#define BM 128
#define BN 128
#define BK 64

DEVFN void store_val(float* p, float v) { *p = v; }
DEVFN void store_val(unsigned short* p, float v) { *p = f2bf(v); }

typedef const __attribute__((address_space(1))) void* gas_ptr;
typedef __attribute__((address_space(3))) void* las_ptr;

DEVFN void async_copy16(const void* g, void* l) {
    __builtin_amdgcn_global_load_lds((gas_ptr)g, (las_ptr)l, 16, 0, 0);
}

template <typename OutT>
__global__ __launch_bounds__(256) void gemm_bt(const unsigned short* __restrict__ A,   // M x K bf16 bits
                                               const unsigned short* __restrict__ B,   // N x K bf16 bits
                                               const float* __restrict__ bias,         // N or nullptr
                                               OutT* __restrict__ C,                   // M x N
                                               int M, int N, int K) {
    __shared__ __align__(16) unsigned short As[BM][BK];
    __shared__ __align__(16) unsigned short Bs[BN][BK];

    const int tid  = threadIdx.x;
    const int wave = tid >> 6;
    const int lane = tid & 63;

    const int tile_m = blockIdx.x * BM;
    const int tile_n = blockIdx.y * BN;

    const int st_row = lane >> 3;          // 0..7 within 8-row chunk
    const int st_k   = (lane & 7) * 8;     // element offset in K

    const int wr = wave >> 1;              // 0..1
    const int wc = wave & 1;               // 0..1
    const int lane_lo = lane & 15;
    const int lane_hi = lane >> 4;         // 0..3

    f32x4 acc[4][4];
#pragma unroll
    for (int i = 0; i < 4; i++)
#pragma unroll
        for (int j = 0; j < 4; j++) acc[i][j] = (f32x4)(0.f);

    for (int k0 = 0; k0 < K; k0 += BK) {
#pragma unroll
        for (int j = 0; j < 4; ++j) {
            int rbase = (j * 4 + wave) * 8;
            const unsigned short* gA = A + (size_t)(tile_m + rbase + st_row) * K + k0 + st_k;
            async_copy16(gA, &As[rbase][0]);
            const unsigned short* gB = B + (size_t)(tile_n + rbase + st_row) * K + k0 + st_k;
            async_copy16(gB, &Bs[rbase][0]);
        }
        __syncthreads();
#pragma unroll
        for (int ks = 0; ks < 2; ++ks) {
            short8 af[4], bf[4];
#pragma unroll
            for (int i = 0; i < 4; i++) {
                int row = wr * 64 + i * 16 + lane_lo;
                af[i] = *(const short8*)&As[row][ks * 32 + lane_hi * 8];
            }
#pragma unroll
            for (int i = 0; i < 4; i++) {
                int row = wc * 64 + i * 16 + lane_lo;
                bf[i] = *(const short8*)&Bs[row][ks * 32 + lane_hi * 8];
            }
#pragma unroll
            for (int i = 0; i < 4; i++)
#pragma unroll
                for (int j = 0; j < 4; j++)
                    acc[i][j] = __builtin_amdgcn_mfma_f32_16x16x32_bf16(af[i], bf[j], acc[i][j], 0, 0, 0);
        }
        __syncthreads();
    }

    // epilogue: C/D layout col = lane&15, row = (lane>>4)*4 + r  (verified m89/m91)
#pragma unroll
    for (int i = 0; i < 4; i++) {
#pragma unroll
        for (int j = 0; j < 4; j++) {
            int col = tile_n + wc * 64 + j * 16 + lane_lo;
            float bv = bias ? bias[col] : 0.f;
            int row0 = tile_m + wr * 64 + i * 16 + lane_hi * 4;
#pragma unroll
            for (int r = 0; r < 4; r++) {
                store_val(&C[(size_t)(row0 + r) * N + col], acc[i][j][r] + bv);
            }
        }
    }
}

// ---------------- scan kernels over fused P = [Pr | Pk | Pv] (M x 3072 fp32) ----------------
// K[t] = epsK*Pk[t-1] + (1-epsK)*Pk[t+1] + bk   (zero rows outside [0,T))
// etc. Shift-combine is fused here via a 3-row register rolling window.
DEVFN float clip_exp(float x) { return expf(fminf(fmaxf(x, -20.f), 10.f)); }

DEVFN float4 zero4() { return make_float4(0.f, 0.f, 0.f, 0.f); }

__global__ __launch_bounds__(256) void scan_partial_kernel(const float* __restrict__ P,
                                                           const float* __restrict__ td,
                                                           const float* __restrict__ bk,
                                                           const float* __restrict__ bv,
                                                           float epsK, float epsV,
                                                           float* __restrict__ pE,
                                                           float* __restrict__ pEV) {
    const int b = blockIdx.x;
    const int n = b / NCH, ch = b % NCH;
    const int c = threadIdx.x * 4;
    const size_t RS = NPROJ;               // row stride in floats

    F4 w; w.v = *(const float4*)(td + c);
#pragma unroll
    for (int j = 0; j < 4; j++) w.a[j] = fmaxf(w.a[j], 0.f);
    F4 bk4; bk4.v = *(const float4*)(bk + c);
    F4 bv4; bv4.v = *(const float4*)(bv + c);

    const int t0 = ch * CHL;
    const float* Pk = P + (size_t)n * TT * RS + CD + c;       // row t -> Pk + t*RS
    const float* Pv = P + (size_t)n * TT * RS + 2 * CD + c;

    F4 km1, k0, kp1, vm1, v0, vp1;
    km1.v = (t0 > 0) ? *(const float4*)(Pk + (size_t)(t0 - 1) * RS) : zero4();
    k0.v  = *(const float4*)(Pk + (size_t)t0 * RS);
    kp1.v = *(const float4*)(Pk + (size_t)(t0 + 1) * RS);
    vm1.v = (t0 > 0) ? *(const float4*)(Pv + (size_t)(t0 - 1) * RS) : zero4();
    v0.v  = *(const float4*)(Pv + (size_t)t0 * RS);
    vp1.v = *(const float4*)(Pv + (size_t)(t0 + 1) * RS);

    const float omK = 1.f - epsK, omV = 1.f - epsV;
    float sE[4] = {0, 0, 0, 0}, sEV[4] = {0, 0, 0, 0};

#pragma unroll 4
    for (int i = 0; i < CHL; ++i) {
        const int t = t0 + i;
        const float trem = (float)(TT - 1 - t);
#pragma unroll
        for (int j = 0; j < 4; j++) {
            float kk = epsK * km1.a[j] + omK * kp1.a[j] + bk4.a[j];
            float vv = epsV * vm1.a[j] + omV * vp1.a[j] + bv4.a[j];
            float e = clip_exp(-w.a[j] * trem + kk);
            sE[j] += e;
            sEV[j] += e * vv;
        }
        km1 = k0; k0 = kp1;
        vm1 = v0; v0 = vp1;
        if (t + 2 < TT) {
            kp1.v = *(const float4*)(Pk + (size_t)(t + 2) * RS);
            vp1.v = *(const float4*)(Pv + (size_t)(t + 2) * RS);
        } else {
            kp1.v = zero4(); vp1.v = zero4();
        }
    }
    size_t pbase = ((size_t)n * NCH + ch) * CD + c;
    F4 oE, oEV;
#pragma unroll
    for (int j = 0; j < 4; j++) { oE.a[j] = sE[j]; oEV.a[j] = sEV[j]; }
    *(float4*)(pE + pbase) = oE.v;
    *(float4*)(pEV + pbase) = oEV.v;
}

__global__ __launch_bounds__(256) void scan_carry_kernel(float* __restrict__ pE,
                                                         float* __restrict__ pEV) {
    int idx = blockIdx.x * 256 + threadIdx.x;   // 0..4095 (n*CD + c)
    int n = idx / CD, c = idx % CD;
    float rE = 0.f, rEV = 0.f;
    for (int ch = 0; ch < NCH; ++ch) {
        size_t p = ((size_t)n * NCH + ch) * CD + c;
        float tE = pE[p];  pE[p]  = rE;  rE  += tE;
        float tV = pEV[p]; pEV[p] = rEV; rEV += tV;
    }
}

__global__ __launch_bounds__(256) void scan_apply_kernel(const float* __restrict__ P,
                                                         const float* __restrict__ td,
                                                         const float* __restrict__ Ub,
                                                         const float* __restrict__ br,
                                                         const float* __restrict__ bk,
                                                         const float* __restrict__ bv,
                                                         float epsR, float epsK, float epsV,
                                                         const float* __restrict__ pE,
                                                         const float* __restrict__ pEV,
                                                         unsigned short* __restrict__ gated) {
    const int b = blockIdx.x;
    const int n = b / NCH, ch = b % NCH;
    const int c = threadIdx.x * 4;
    const size_t RS = NPROJ;

    F4 w; w.v = *(const float4*)(td + c);
#pragma unroll
    for (int j = 0; j < 4; j++) w.a[j] = fmaxf(w.a[j], 0.f);
    F4 u;   u.v   = *(const float4*)(Ub + c);
    F4 br4; br4.v = *(const float4*)(br + c);
    F4 bk4; bk4.v = *(const float4*)(bk + c);
    F4 bv4; bv4.v = *(const float4*)(bv + c);

    const int t0 = ch * CHL;
    const float* Pr = P + (size_t)n * TT * RS + c;
    const float* Pk = Pr + CD;
    const float* Pv = Pr + 2 * CD;

    F4 rm1, r0, rp1, km1, k0, kp1, vm1, v0, vp1;
    rm1.v = (t0 > 0) ? *(const float4*)(Pr + (size_t)(t0 - 1) * RS) : zero4();
    r0.v  = *(const float4*)(Pr + (size_t)t0 * RS);
    rp1.v = *(const float4*)(Pr + (size_t)(t0 + 1) * RS);
    km1.v = (t0 > 0) ? *(const float4*)(Pk + (size_t)(t0 - 1) * RS) : zero4();
    k0.v  = *(const float4*)(Pk + (size_t)t0 * RS);
    kp1.v = *(const float4*)(Pk + (size_t)(t0 + 1) * RS);
    vm1.v = (t0 > 0) ? *(const float4*)(Pv + (size_t)(t0 - 1) * RS) : zero4();
    v0.v  = *(const float4*)(Pv + (size_t)t0 * RS);
    vp1.v = *(const float4*)(Pv + (size_t)(t0 + 1) * RS);

    size_t pbase = ((size_t)n * NCH + ch) * CD + c;
    F4 cE, cEV;
    cE.v  = *(const float4*)(pE + pbase);
    cEV.v = *(const float4*)(pEV + pbase);

    const float omR = 1.f - epsR, omK = 1.f - epsK, omV = 1.f - epsV;
    unsigned short* gbase = gated + ((size_t)n * TT + t0) * CD + c;

#pragma unroll 4
    for (int i = 0; i < CHL; ++i) {
        const int t = t0 + i;
        const float trem = (float)(TT - 1 - t);
        ushort4 og;
        unsigned short* ogp = (unsigned short*)&og;
#pragma unroll
        for (int j = 0; j < 4; j++) {
            float kk = epsK * km1.a[j] + omK * kp1.a[j] + bk4.a[j];
            float vv = epsV * vm1.a[j] + omV * vp1.a[j] + bv4.a[j];
            float rr = epsR * rm1.a[j] + omR * rp1.a[j] + br4.a[j];
            float e  = clip_exp(-w.a[j] * trem + kk);
            float eu = clip_exp(u.a[j] + kk);
            float Aj = cEV.a[j] + eu * vv;
            float Bj = cE.a[j] + eu;
            float wkv = Aj / Bj;
            float sig = 1.f / (1.f + expf(-rr));
            ogp[j] = f2bf(sig * wkv);
            cEV.a[j] += e * vv;
            cE.a[j]  += e;
        }
        *(ushort4*)(gbase + (size_t)i * CD) = og;
        rm1 = r0; r0 = rp1;
        km1 = k0; k0 = kp1;
        vm1 = v0; v0 = vp1;
        if (t + 2 < TT) {
            rp1.v = *(const float4*)(Pr + (size_t)(t + 2) * RS);
            kp1.v = *(const float4*)(Pk + (size_t)(t + 2) * RS);
            vp1.v = *(const float4*)(Pv + (size_t)(t + 2) * RS);
        } else {
            rp1.v = zero4(); kp1.v = zero4(); vp1.v = zero4();
        }
    }
}

// ---------------- launcher ----------------
extern "C" void kernel_launch(void* const* d_in, const int* in_sizes, int n_in,
                              void* d_out, int out_size, void* d_ws, size_t ws_size,
                              hipStream_t stream) {
    const float* x  = (const float*)d_in[0];
    const float* Wr = (const float*)d_in[1];
    const float* br = (const float*)d_in[2];
    const float* Wk = (const float*)d_in[3];
    const float* bk = (const float*)d_in[4];
    const float* Wv = (const float*)d_in[5];
    const float* bv = (const float*)d_in[6];
    const float* Wo = (const float*)d_in[7];
    const float* bo = (const float*)d_in[8];
    const float* td = (const float*)d_in[9];
    const float* U  = (const float*)d_in[10];
    float* out = (float*)d_out;

    // eps constants (host-side, double precision like the reference)
    const double eps0 = std::exp(-1.0 / 12.0);
    const float epsR = (float)(eps0 / 2.0);
    const float epsK = (float)(eps0 + 0.3 * 1.0 / 11.0);
    const float epsV = (float)eps0;

    // workspace carve-up (~124 MB of the 256 MiB d_ws)
    char* p = (char*)d_ws;
    auto take = [&](size_t bytes) { char* q = p; p += (bytes + 255) & ~(size_t)255; return q; };
    unsigned short* Wcat_bf = (unsigned short*)take((size_t)NPROJ * CD * 2);  // [Wr;Wk;Wv] bf16
    unsigned short* Wo_bf   = (unsigned short*)take((size_t)CD * CD * 2);
    unsigned short* xbf     = (unsigned short*)take((size_t)MROWS * CD * 2);  // x bf16, later reused as gated
    float*          Pbuf    = (float*)take((size_t)MROWS * NPROJ * 4);        // fused projections fp32
    float*          pE      = (float*)take((size_t)NB * NCH * CD * 4);
    float*          pEV     = (float*)take((size_t)NB * NCH * CD * 4);

    const int wn4 = CD * CD / 4;           // 262144
    cast_bf16_kernel<<<wn4 / 256, 256, 0, stream>>>(Wr, Wcat_bf, wn4);
    cast_bf16_kernel<<<wn4 / 256, 256, 0, stream>>>(Wk, Wcat_bf + (size_t)CD * CD, wn4);
    cast_bf16_kernel<<<wn4 / 256, 256, 0, stream>>>(Wv, Wcat_bf + (size_t)2 * CD * CD, wn4);
    cast_bf16_kernel<<<wn4 / 256, 256, 0, stream>>>(Wo, Wo_bf, wn4);

    const int in4 = MROWS * CD / 4;        // 2097152
    cast_bf16_kernel<<<in4 / 256, 256, 0, stream>>>(x, xbf, in4);

    // fused R/K/V projection: P = x_bf @ Wcat^T   (bias folded into scan combine)
    dim3 g1(MROWS / BM, NPROJ / BN);       // 64 x 24
    gemm_bt<float><<<g1, 256, 0, stream>>>(xbf, Wcat_bf, nullptr, Pbuf, MROWS, NPROJ, CD);

    scan_partial_kernel<<<NB * NCH, 256, 0, stream>>>(Pbuf, td, bk, bv, epsK, epsV, pE, pEV);
    scan_carry_kernel<<<(NB * CD) / 256, 256, 0, stream>>>(pE, pEV);
    scan_apply_kernel<<<NB * NCH, 256, 0, stream>>>(Pbuf, td, U, br, bk, bv, epsR, epsK, epsV,
                                                    pE, pEV, xbf);

    // output GEMM
    dim3 g2(MROWS / BM, CD / BN);          // 64 x 8
    gemm_bt<float><<<g2, 256, 0, stream>>>(xbf, Wo_bf, bo, out, MROWS, CD, CD);
}

// Round 3
// 274.745 us; speedup vs baseline: 1.1279x; 1.0001x over previous
//
#include <hip/hip_runtime.h>
#include <cmath>

#define DEVFN __device__ __forceinline__

// Problem constants
constexpr int NB = 4;        // batch
constexpr int TT = 2048;     // sequence
constexpr int CD = 1024;     // channels (= H*HS)
constexpr int MROWS = NB * TT;   // 8192
constexpr int NPROJ = 3 * CD;    // fused R/K/V projection width = 3072
constexpr int NCH = 128;     // scan chunks over T
constexpr int CHL = TT / NCH;    // 16 steps per chunk

// ---------------- bf16 bit helpers (RNE) ----------------
DEVFN float bf2f(unsigned short u) {
    union { unsigned int i; float f; } z; z.i = ((unsigned int)u) << 16; return z.f;
}
DEVFN unsigned short f2bf(float f) {
    union { float f; unsigned int i; } z; z.f = f;
    unsigned int r = z.i + 0x7FFFu + ((z.i >> 16) & 1u);
    return (unsigned short)(r >> 16);
}

union F4 { float4 v; float a[4]; };

DEVFN F4 ld_bf4(const unsigned short* p) {
    ushort4 u = *(const ushort4*)p;
    F4 r; r.a[0] = bf2f(u.x); r.a[1] = bf2f(u.y); r.a[2] = bf2f(u.z); r.a[3] = bf2f(u.w);
    return r;
}
DEVFN F4 zero4f() { F4 r; r.a[0] = r.a[1] = r.a[2] = r.a[3] = 0.f; return r; }

// ---------------- cast fp32 -> bf16 bits ----------------
__global__ __launch_bounds__(256) void cast_bf16_kernel(const float* __restrict__ src,
                                                        unsigned short* __restrict__ dst, int n4) {
    int i = blockIdx.x * 256 + threadIdx.x;
    if (i >= n4) return;
    float4 v = ((const float4*)src)[i];
    ushort4 o;
    o.x = f2bf(v.x); o.y = f2bf(v.y); o.z = f2bf(v.z); o.w = f2bf(v.w);
    ((ushort4*)dst)[i] = o;
}

// ---------------- bf16 MFMA GEMM:  C[M,N] = A[M,K] @ B[N,K]^T (+ bias)  (m97 recipe) ----------------
typedef __attribute__((ext_vector_type(8))) short short8;   // 8 bf16 (4 VGPRs)
typedef __attribute__((ext_vector_type(4))) float f32x4;

#define BM 128
#define BN 128
#define BK 64

DEVFN void store_val(float* p, float v) { *p = v; }
DEVFN void store_val(unsigned short* p, float v) { *p = f2bf(v); }

typedef const __attribute__((address_space(1))) void* gas_ptr;
typedef __attribute__((address_space(3))) void* las_ptr;

DEVFN void async_copy16(const void* g, void* l) {
    __builtin_amdgcn_global_load_lds((gas_ptr)g, (las_ptr)l, 16, 0, 0);
}

template <typename OutT>
__global__ __launch_bounds__(256) void gemm_bt(const unsigned short* __restrict__ A,   // M x K bf16 bits
                                               const unsigned short* __restrict__ B,   // N x K bf16 bits
                                               const float* __restrict__ bias,         // N or nullptr
                                               OutT* __restrict__ C,                   // M x N
                                               int M, int N, int K) {
    __shared__ __align__(16) unsigned short As[BM][BK];
    __shared__ __align__(16) unsigned short Bs[BN][BK];

    const int tid  = threadIdx.x;
    const int wave = tid >> 6;
    const int lane = tid & 63;

    const int tile_m = blockIdx.x * BM;
    const int tile_n = blockIdx.y * BN;

    const int st_row = lane >> 3;          // 0..7 within 8-row chunk
    const int st_k   = (lane & 7) * 8;     // element offset in K

    const int wr = wave >> 1;              // 0..1
    const int wc = wave & 1;               // 0..1
    const int lane_lo = lane & 15;
    const int lane_hi = lane >> 4;         // 0..3

    f32x4 acc[4][4];
#pragma unroll
    for (int i = 0; i < 4; i++)
#pragma unroll
        for (int j = 0; j < 4; j++) acc[i][j] = (f32x4)(0.f);

    for (int k0 = 0; k0 < K; k0 += BK) {
#pragma unroll
        for (int j = 0; j < 4; ++j) {
            int rbase = (j * 4 + wave) * 8;
            const unsigned short* gA = A + (size_t)(tile_m + rbase + st_row) * K + k0 + st_k;
            async_copy16(gA, &As[rbase][0]);
            const unsigned short* gB = B + (size_t)(tile_n + rbase + st_row) * K + k0 + st_k;
            async_copy16(gB, &Bs[rbase][0]);
        }
        __syncthreads();
#pragma unroll
        for (int ks = 0; ks < 2; ++ks) {
            short8 af[4], bf[4];
#pragma unroll
            for (int i = 0; i < 4; i++) {
                int row = wr * 64 + i * 16 + lane_lo;
                af[i] = *(const short8*)&As[row][ks * 32 + lane_hi * 8];
            }
#pragma unroll
            for (int i = 0; i < 4; i++) {
                int row = wc * 64 + i * 16 + lane_lo;
                bf[i] = *(const short8*)&Bs[row][ks * 32 + lane_hi * 8];
            }
#pragma unroll
            for (int i = 0; i < 4; i++)
#pragma unroll
                for (int j = 0; j < 4; j++)
                    acc[i][j] = __builtin_amdgcn_mfma_f32_16x16x32_bf16(af[i], bf[j], acc[i][j], 0, 0, 0);
        }
        __syncthreads();
    }

    // epilogue: C/D layout col = lane&15, row = (lane>>4)*4 + r  (verified m89/m91)
#pragma unroll
    for (int i = 0; i < 4; i++) {
#pragma unroll
        for (int j = 0; j < 4; j++) {
            int col = tile_n + wc * 64 + j * 16 + lane_lo;
            float bv = bias ? bias[col] : 0.f;
            int row0 = tile_m + wr * 64 + i * 16 + lane_hi * 4;
#pragma unroll
            for (int r = 0; r < 4; r++) {
                store_val(&C[(size_t)(row0 + r) * N + col], acc[i][j][r] + bv);
            }
        }
    }
}

// ---------------- scan kernels over fused P = [Pr | Pk | Pv] (M x 3072 bf16) ----------------
// K[t] = epsK*Pk[t-1] + (1-epsK)*Pk[t+1] + bk   (zero rows outside [0,T))
// Shift-combine fused via a 3-row register rolling window.
DEVFN float clip_exp(float x) { return expf(fminf(fmaxf(x, -20.f), 10.f)); }

__global__ __launch_bounds__(256) void scan_partial_kernel(const unsigned short* __restrict__ P,
                                                           const float* __restrict__ td,
                                                           const float* __restrict__ bk,
                                                           const float* __restrict__ bv,
                                                           float epsK, float epsV,
                                                           float* __restrict__ pE,
                                                           float* __restrict__ pEV) {
    const int b = blockIdx.x;
    const int n = b / NCH, ch = b % NCH;
    const int c = threadIdx.x * 4;
    const size_t RS = NPROJ;               // row stride in elements

    F4 w; w.v = *(const float4*)(td + c);
#pragma unroll
    for (int j = 0; j < 4; j++) w.a[j] = fmaxf(w.a[j], 0.f);
    F4 bk4; bk4.v = *(const float4*)(bk + c);
    F4 bv4; bv4.v = *(const float4*)(bv + c);

    const int t0 = ch * CHL;
    const unsigned short* Pk = P + (size_t)n * TT * RS + CD + c;       // row t -> Pk + t*RS
    const unsigned short* Pv = P + (size_t)n * TT * RS + 2 * CD + c;

    F4 km1, k0, kp1, vm1, v0, vp1;
    km1 = (t0 > 0) ? ld_bf4(Pk + (size_t)(t0 - 1) * RS) : zero4f();
    k0  = ld_bf4(Pk + (size_t)t0 * RS);
    kp1 = ld_bf4(Pk + (size_t)(t0 + 1) * RS);
    vm1 = (t0 > 0) ? ld_bf4(Pv + (size_t)(t0 - 1) * RS) : zero4f();
    v0  = ld_bf4(Pv + (size_t)t0 * RS);
    vp1 = ld_bf4(Pv + (size_t)(t0 + 1) * RS);

    const float omK = 1.f - epsK, omV = 1.f - epsV;
    float sE[4] = {0, 0, 0, 0}, sEV[4] = {0, 0, 0, 0};

#pragma unroll 4
    for (int i = 0; i < CHL; ++i) {
        const int t = t0 + i;
        const float trem = (float)(TT - 1 - t);
#pragma unroll
        for (int j = 0; j < 4; j++) {
            float kk = epsK * km1.a[j] + omK * kp1.a[j] + bk4.a[j];
            float vv = epsV * vm1.a[j] + omV * vp1.a[j] + bv4.a[j];
            float e = clip_exp(-w.a[j] * trem + kk);
            sE[j] += e;
            sEV[j] += e * vv;
        }
        km1 = k0; k0 = kp1;
        vm1 = v0; v0 = vp1;
        if (t + 2 < TT) {
            kp1 = ld_bf4(Pk + (size_t)(t + 2) * RS);
            vp1 = ld_bf4(Pv + (size_t)(t + 2) * RS);
        } else {
            kp1 = zero4f(); vp1 = zero4f();
        }
    }
    size_t pbase = ((size_t)n * NCH + ch) * CD + c;
    F4 oE, oEV;
#pragma unroll
    for (int j = 0; j < 4; j++) { oE.a[j] = sE[j]; oEV.a[j] = sEV[j]; }
    *(float4*)(pE + pbase) = oE.v;
    *(float4*)(pEV + pbase) = oEV.v;
}

__global__ __launch_bounds__(256) void scan_carry_kernel(float* __restrict__ pE,
                                                         float* __restrict__ pEV) {
    int idx = blockIdx.x * 256 + threadIdx.x;   // 0..4095 (n*CD + c)
    int n = idx / CD, c = idx % CD;
    float rE = 0.f, rEV = 0.f;
    for (int ch = 0; ch < NCH; ++ch) {
        size_t p = ((size_t)n * NCH + ch) * CD + c;
        float tE = pE[p];  pE[p]  = rE;  rE  += tE;
        float tV = pEV[p]; pEV[p] = rEV; rEV += tV;
    }
}

__global__ __launch_bounds__(256) void scan_apply_kernel(const unsigned short* __restrict__ P,
                                                         const float* __restrict__ td,
                                                         const float* __restrict__ Ub,
                                                         const float* __restrict__ br,
                                                         const float* __restrict__ bk,
                                                         const float* __restrict__ bv,
                                                         float epsR, float epsK, float epsV,
                                                         const float* __restrict__ pE,
                                                         const float* __restrict__ pEV,
                                                         unsigned short* __restrict__ gated) {
    const int b = blockIdx.x;
    const int n = b / NCH, ch = b % NCH;
    const int c = threadIdx.x * 4;
    const size_t RS = NPROJ;

    F4 w; w.v = *(const float4*)(td + c);
#pragma unroll
    for (int j = 0; j < 4; j++) w.a[j] = fmaxf(w.a[j], 0.f);
    F4 u;   u.v   = *(const float4*)(Ub + c);
    F4 br4; br4.v = *(const float4*)(br + c);
    F4 bk4; bk4.v = *(const float4*)(bk + c);
    F4 bv4; bv4.v = *(const float4*)(bv + c);

    const int t0 = ch * CHL;
    const unsigned short* Pr = P + (size_t)n * TT * RS + c;
    const unsigned short* Pk = Pr + CD;
    const unsigned short* Pv = Pr + 2 * CD;

    F4 rm1, r0, rp1, km1, k0, kp1, vm1, v0, vp1;
    rm1 = (t0 > 0) ? ld_bf4(Pr + (size_t)(t0 - 1) * RS) : zero4f();
    r0  = ld_bf4(Pr + (size_t)t0 * RS);
    rp1 = ld_bf4(Pr + (size_t)(t0 + 1) * RS);
    km1 = (t0 > 0) ? ld_bf4(Pk + (size_t)(t0 - 1) * RS) : zero4f();
    k0  = ld_bf4(Pk + (size_t)t0 * RS);
    kp1 = ld_bf4(Pk + (size_t)(t0 + 1) * RS);
    vm1 = (t0 > 0) ? ld_bf4(Pv + (size_t)(t0 - 1) * RS) : zero4f();
    v0  = ld_bf4(Pv + (size_t)t0 * RS);
    vp1 = ld_bf4(Pv + (size_t)(t0 + 1) * RS);

    size_t pbase = ((size_t)n * NCH + ch) * CD + c;
    F4 cE, cEV;
    cE.v  = *(const float4*)(pE + pbase);
    cEV.v = *(const float4*)(pEV + pbase);

    const float omR = 1.f - epsR, omK = 1.f - epsK, omV = 1.f - epsV;
    unsigned short* gbase = gated + ((size_t)n * TT + t0) * CD + c;

#pragma unroll 4
    for (int i = 0; i < CHL; ++i) {
        const int t = t0 + i;
        const float trem = (float)(TT - 1 - t);
        ushort4 og;
        unsigned short* ogp = (unsigned short*)&og;
#pragma unroll
        for (int j = 0; j < 4; j++) {
            float kk = epsK * km1.a[j] + omK * kp1.a[j] + bk4.a[j];
            float vv = epsV * vm1.a[j] + omV * vp1.a[j] + bv4.a[j];
            float rr = epsR * rm1.a[j] + omR * rp1.a[j] + br4.a[j];
            float e  = clip_exp(-w.a[j] * trem + kk);
            float eu = clip_exp(u.a[j] + kk);
            float Aj = cEV.a[j] + eu * vv;
            float Bj = cE.a[j] + eu;
            float wkv = Aj / Bj;
            float sig = 1.f / (1.f + expf(-rr));
            ogp[j] = f2bf(sig * wkv);
            cEV.a[j] += e * vv;
            cE.a[j]  += e;
        }
        *(ushort4*)(gbase + (size_t)i * CD) = og;
        rm1 = r0; r0 = rp1;
        km1 = k0; k0 = kp1;
        vm1 = v0; v0 = vp1;
        if (t + 2 < TT) {
            rp1 = ld_bf4(Pr + (size_t)(t + 2) * RS);
            kp1 = ld_bf4(Pk + (size_t)(t + 2) * RS);
            vp1 = ld_bf4(Pv + (size_t)(t + 2) * RS);
        } else {
            rp1 = zero4f(); kp1 = zero4f(); vp1 = zero4f();
        }
    }
}

// ---------------- launcher ----------------
extern "C" void kernel_launch(void* const* d_in, const int* in_sizes, int n_in,
                              void* d_out, int out_size, void* d_ws, size_t ws_size,
                              hipStream_t stream) {
    const float* x  = (const float*)d_in[0];
    const float* Wr = (const float*)d_in[1];
    const float* br = (const float*)d_in[2];
    const float* Wk = (const float*)d_in[3];
    const float* bk = (const float*)d_in[4];
    const float* Wv = (const float*)d_in[5];
    const float* bv = (const float*)d_in[6];
    const float* Wo = (const float*)d_in[7];
    const float* bo = (const float*)d_in[8];
    const float* td = (const float*)d_in[9];
    const float* U  = (const float*)d_in[10];
    float* out = (float*)d_out;

    // eps constants (host-side, double precision like the reference)
    const double eps0 = std::exp(-1.0 / 12.0);
    const float epsR = (float)(eps0 / 2.0);
    const float epsK = (float)(eps0 + 0.3 * 1.0 / 11.0);
    const float epsV = (float)eps0;

    // workspace carve-up (~74 MB of d_ws)
    char* p = (char*)d_ws;
    auto take = [&](size_t bytes) { char* q = p; p += (bytes + 255) & ~(size_t)255; return q; };
    unsigned short* Wcat_bf = (unsigned short*)take((size_t)NPROJ * CD * 2);  // [Wr;Wk;Wv] bf16
    unsigned short* Wo_bf   = (unsigned short*)take((size_t)CD * CD * 2);
    unsigned short* xbf     = (unsigned short*)take((size_t)MROWS * CD * 2);  // x bf16, later reused as gated
    unsigned short* Pbuf    = (unsigned short*)take((size_t)MROWS * NPROJ * 2); // fused projections bf16
    float*          pE      = (float*)take((size_t)NB * NCH * CD * 4);
    float*          pEV     = (float*)take((size_t)NB * NCH * CD * 4);

    const int wn4 = CD * CD / 4;           // 262144
    cast_bf16_kernel<<<wn4 / 256, 256, 0, stream>>>(Wr, Wcat_bf, wn4);
    cast_bf16_kernel<<<wn4 / 256, 256, 0, stream>>>(Wk, Wcat_bf + (size_t)CD * CD, wn4);
    cast_bf16_kernel<<<wn4 / 256, 256, 0, stream>>>(Wv, Wcat_bf + (size_t)2 * CD * CD, wn4);
    cast_bf16_kernel<<<wn4 / 256, 256, 0, stream>>>(Wo, Wo_bf, wn4);

    const int in4 = MROWS * CD / 4;        // 2097152
    cast_bf16_kernel<<<in4 / 256, 256, 0, stream>>>(x, xbf, in4);

    // fused R/K/V projection: P = x_bf @ Wcat^T  (bias folded into scan combine), bf16 out
    dim3 g1(MROWS / BM, NPROJ / BN);       // 64 x 24
    gemm_bt<unsigned short><<<g1, 256, 0, stream>>>(xbf, Wcat_bf, nullptr, Pbuf, MROWS, NPROJ, CD);

    scan_partial_kernel<<<NB * NCH, 256, 0, stream>>>(Pbuf, td, bk, bv, epsK, epsV, pE, pEV);
    scan_carry_kernel<<<(NB * CD) / 256, 256, 0, stream>>>(pE, pEV);
    scan_apply_kernel<<<NB * NCH, 256, 0, stream>>>(Pbuf, td, U, br, bk, bv, epsR, epsK, epsV,
                                                    pE, pEV, xbf);

    // output GEMM (fp32 out, required by harness)
    dim3 g2(MROWS / BM, CD / BN);          // 64 x 8
    gemm_bt<float><<<g2, 256, 0, stream>>>(xbf, Wo_bf, bo, out, MROWS, CD, CD);
}

// Round 4
// 243.238 us; speedup vs baseline: 1.2740x; 1.1295x over previous
//
#include <hip/hip_runtime.h>
#include <cmath>

#define DEVFN __device__ __forceinline__

// Problem constants
constexpr int NB = 4;        // batch
constexpr int TT = 2048;     // sequence
constexpr int CD = 1024;     // channels (= H*HS)
constexpr int MROWS = NB * TT;   // 8192
constexpr int NPROJ = 3 * CD;    // fused R/K/V projection width = 3072
constexpr int NCH = 128;     // scan chunks over T
constexpr int CHL = TT / NCH;    // 16 steps per chunk

// ---------------- bf16 bit helpers (RNE) ----------------
DEVFN float bf2f(unsigned short u) {
    union { unsigned int i; float f; } z; z.i = ((unsigned int)u) << 16; return z.f;
}
DEVFN unsigned short f2bf(float f) {
    union { float f; unsigned int i; } z; z.f = f;
    unsigned int r = z.i + 0x7FFFu + ((z.i >> 16) & 1u);
    return (unsigned short)(r >> 16);
}

union F4 { float4 v; float a[4]; };

DEVFN F4 ld_bf4(const unsigned short* p) {
    ushort4 u = *(const ushort4*)p;
    F4 r; r.a[0] = bf2f(u.x); r.a[1] = bf2f(u.y); r.a[2] = bf2f(u.z); r.a[3] = bf2f(u.w);
    return r;
}
DEVFN F4 zero4f() { F4 r; r.a[0] = r.a[1] = r.a[2] = r.a[3] = 0.f; return r; }

// ---------------- fused cast fp32 -> bf16 (weights + x, one dispatch) ----------------
constexpr int WQ = CD * CD / 4;           // 262144 float4 per weight matrix
constexpr int XQ = MROWS * CD / 4;        // 2097152 float4 for x
__global__ __launch_bounds__(256) void cast_all_kernel(const float* __restrict__ Wr,
                                                       const float* __restrict__ Wk,
                                                       const float* __restrict__ Wv,
                                                       const float* __restrict__ Wo,
                                                       const float* __restrict__ x,
                                                       unsigned short* __restrict__ Wcat,
                                                       unsigned short* __restrict__ Wo_bf,
                                                       unsigned short* __restrict__ xbf) {
    int i = blockIdx.x * 256 + threadIdx.x;
    const float* src; unsigned short* dst; int off;
    if (i < 3 * WQ) {
        int r = i / WQ; off = i - r * WQ;
        src = (r == 0) ? Wr : (r == 1) ? Wk : Wv;
        dst = Wcat + (size_t)r * CD * CD;
    } else if (i < 4 * WQ) {
        src = Wo; dst = Wo_bf; off = i - 3 * WQ;
    } else {
        src = x; dst = xbf; off = i - 4 * WQ;
        if (off >= XQ) return;
    }
    float4 v = ((const float4*)src)[off];
    ushort4 o;
    o.x = f2bf(v.x); o.y = f2bf(v.y); o.z = f2bf(v.z); o.w = f2bf(v.w);
    ((ushort4*)dst)[off] = o;
}

// ---------------- bf16 MFMA GEMM:  C[M,N] = A[M,K] @ B[N,K]^T (+ bias) ----------------
// m97 recipe + XOR bank-conflict swizzle: LDS slot [row][g] holds global K-group g^(row&7),
// achieved by permuting the global source address per lane (global_load_lds dest is
// wave-uniform base + lane*16, so the *source* carries the permutation).
typedef __attribute__((ext_vector_type(8))) short short8;   // 8 bf16 (4 VGPRs)
typedef __attribute__((ext_vector_type(4))) float f32x4;

#define BM 128
#define BN 128
#define BK 64

DEVFN void store_val(float* p, float v) { *p = v; }
DEVFN void store_val(unsigned short* p, float v) { *p = f2bf(v); }

typedef const __attribute__((address_space(1))) void* gas_ptr;
typedef __attribute__((address_space(3))) void* las_ptr;

DEVFN void async_copy16(const void* g, void* l) {
    __builtin_amdgcn_global_load_lds((gas_ptr)g, (las_ptr)l, 16, 0, 0);
}

template <typename OutT>
__global__ __launch_bounds__(256) void gemm_bt(const unsigned short* __restrict__ A,   // M x K bf16 bits
                                               const unsigned short* __restrict__ B,   // N x K bf16 bits
                                               const float* __restrict__ bias,         // N or nullptr
                                               OutT* __restrict__ C,                   // M x N
                                               int M, int N, int K) {
    __shared__ __align__(16) unsigned short As[BM][BK];
    __shared__ __align__(16) unsigned short Bs[BN][BK];

    const int tid  = threadIdx.x;
    const int wave = tid >> 6;
    const int lane = tid & 63;

    const int tile_m = blockIdx.x * BM;
    const int tile_n = blockIdx.y * BN;

    const int st_row = lane >> 3;                    // 0..7 within 8-row chunk
    const int st_k   = (((lane & 7) ^ st_row) * 8);  // XOR-swizzled source K-group

    const int wr = wave >> 1;              // 0..1
    const int wc = wave & 1;               // 0..1
    const int lane_lo = lane & 15;
    const int lane_hi = lane >> 4;         // 0..3
    const int sw_m = lane_lo & 7;          // row&7 for fragment rows

    f32x4 acc[4][4];
#pragma unroll
    for (int i = 0; i < 4; i++)
#pragma unroll
        for (int j = 0; j < 4; j++) acc[i][j] = (f32x4)(0.f);

    for (int k0 = 0; k0 < K; k0 += BK) {
#pragma unroll
        for (int j = 0; j < 4; ++j) {
            int rbase = (j * 4 + wave) * 8;
            const unsigned short* gA = A + (size_t)(tile_m + rbase + st_row) * K + k0 + st_k;
            async_copy16(gA, &As[rbase][0]);
            const unsigned short* gB = B + (size_t)(tile_n + rbase + st_row) * K + k0 + st_k;
            async_copy16(gB, &Bs[rbase][0]);
        }
        __syncthreads();
#pragma unroll
        for (int ks = 0; ks < 2; ++ks) {
            short8 af[4], bf[4];
            const int kgrpA = ((ks * 4 + lane_hi) ^ sw_m) * 8;   // swizzled read group
#pragma unroll
            for (int i = 0; i < 4; i++) {
                int row = wr * 64 + i * 16 + lane_lo;
                af[i] = *(const short8*)&As[row][kgrpA];
            }
#pragma unroll
            for (int i = 0; i < 4; i++) {
                int row = wc * 64 + i * 16 + lane_lo;
                bf[i] = *(const short8*)&Bs[row][kgrpA];
            }
#pragma unroll
            for (int i = 0; i < 4; i++)
#pragma unroll
                for (int j = 0; j < 4; j++)
                    acc[i][j] = __builtin_amdgcn_mfma_f32_16x16x32_bf16(af[i], bf[j], acc[i][j], 0, 0, 0);
        }
        __syncthreads();
    }

    // epilogue: C/D layout col = lane&15, row = (lane>>4)*4 + r  (verified m89/m91)
#pragma unroll
    for (int i = 0; i < 4; i++) {
#pragma unroll
        for (int j = 0; j < 4; j++) {
            int col = tile_n + wc * 64 + j * 16 + lane_lo;
            float bv = bias ? bias[col] : 0.f;
            int row0 = tile_m + wr * 64 + i * 16 + lane_hi * 4;
#pragma unroll
            for (int r = 0; r < 4; r++) {
                store_val(&C[(size_t)(row0 + r) * N + col], acc[i][j][r] + bv);
            }
        }
    }
}

// ---------------- scan kernels over fused P = [Pr | Pk | Pv] (M x 3072 bf16) ----------------
DEVFN float clip_exp(float x) { return expf(fminf(fmaxf(x, -20.f), 10.f)); }

__global__ __launch_bounds__(256) void scan_partial_kernel(const unsigned short* __restrict__ P,
                                                           const float* __restrict__ td,
                                                           const float* __restrict__ bk,
                                                           const float* __restrict__ bv,
                                                           float epsK, float epsV,
                                                           float* __restrict__ pE,
                                                           float* __restrict__ pEV) {
    const int b = blockIdx.x;
    const int n = b / NCH, ch = b % NCH;
    const int c = threadIdx.x * 4;
    const size_t RS = NPROJ;               // row stride in elements

    F4 w; w.v = *(const float4*)(td + c);
#pragma unroll
    for (int j = 0; j < 4; j++) w.a[j] = fmaxf(w.a[j], 0.f);
    F4 bk4; bk4.v = *(const float4*)(bk + c);
    F4 bv4; bv4.v = *(const float4*)(bv + c);

    const int t0 = ch * CHL;
    const unsigned short* Pk = P + (size_t)n * TT * RS + CD + c;       // row t -> Pk + t*RS
    const unsigned short* Pv = P + (size_t)n * TT * RS + 2 * CD + c;

    F4 km1, k0, kp1, vm1, v0, vp1;
    km1 = (t0 > 0) ? ld_bf4(Pk + (size_t)(t0 - 1) * RS) : zero4f();
    k0  = ld_bf4(Pk + (size_t)t0 * RS);
    kp1 = ld_bf4(Pk + (size_t)(t0 + 1) * RS);
    vm1 = (t0 > 0) ? ld_bf4(Pv + (size_t)(t0 - 1) * RS) : zero4f();
    v0  = ld_bf4(Pv + (size_t)t0 * RS);
    vp1 = ld_bf4(Pv + (size_t)(t0 + 1) * RS);

    const float omK = 1.f - epsK, omV = 1.f - epsV;
    float sE[4] = {0, 0, 0, 0}, sEV[4] = {0, 0, 0, 0};

#pragma unroll 4
    for (int i = 0; i < CHL; ++i) {
        const int t = t0 + i;
        const float trem = (float)(TT - 1 - t);
#pragma unroll
        for (int j = 0; j < 4; j++) {
            float kk = epsK * km1.a[j] + omK * kp1.a[j] + bk4.a[j];
            float vv = epsV * vm1.a[j] + omV * vp1.a[j] + bv4.a[j];
            float e = clip_exp(-w.a[j] * trem + kk);
            sE[j] += e;
            sEV[j] += e * vv;
        }
        km1 = k0; k0 = kp1;
        vm1 = v0; v0 = vp1;
        if (t + 2 < TT) {
            kp1 = ld_bf4(Pk + (size_t)(t + 2) * RS);
            vp1 = ld_bf4(Pv + (size_t)(t + 2) * RS);
        } else {
            kp1 = zero4f(); vp1 = zero4f();
        }
    }
    size_t pbase = ((size_t)n * NCH + ch) * CD + c;
    F4 oE, oEV;
#pragma unroll
    for (int j = 0; j < 4; j++) { oE.a[j] = sE[j]; oEV.a[j] = sEV[j]; }
    *(float4*)(pE + pbase) = oE.v;
    *(float4*)(pEV + pbase) = oEV.v;
}

__global__ __launch_bounds__(256) void scan_carry_kernel(float* __restrict__ pE,
                                                         float* __restrict__ pEV) {
    int idx = blockIdx.x * 256 + threadIdx.x;   // 0..4095 (n*CD + c)
    int n = idx / CD, c = idx % CD;
    float rE = 0.f, rEV = 0.f;
    for (int ch = 0; ch < NCH; ++ch) {
        size_t p = ((size_t)n * NCH + ch) * CD + c;
        float tE = pE[p];  pE[p]  = rE;  rE  += tE;
        float tV = pEV[p]; pEV[p] = rEV; rEV += tV;
    }
}

__global__ __launch_bounds__(256) void scan_apply_kernel(const unsigned short* __restrict__ P,
                                                         const float* __restrict__ td,
                                                         const float* __restrict__ Ub,
                                                         const float* __restrict__ br,
                                                         const float* __restrict__ bk,
                                                         const float* __restrict__ bv,
                                                         float epsR, float epsK, float epsV,
                                                         const float* __restrict__ pE,
                                                         const float* __restrict__ pEV,
                                                         unsigned short* __restrict__ gated) {
    const int b = blockIdx.x;
    const int n = b / NCH, ch = b % NCH;
    const int c = threadIdx.x * 4;
    const size_t RS = NPROJ;

    F4 w; w.v = *(const float4*)(td + c);
#pragma unroll
    for (int j = 0; j < 4; j++) w.a[j] = fmaxf(w.a[j], 0.f);
    F4 u;   u.v   = *(const float4*)(Ub + c);
    F4 br4; br4.v = *(const float4*)(br + c);
    F4 bk4; bk4.v = *(const float4*)(bk + c);
    F4 bv4; bv4.v = *(const float4*)(bv + c);

    const int t0 = ch * CHL;
    const unsigned short* Pr = P + (size_t)n * TT * RS + c;
    const unsigned short* Pk = Pr + CD;
    const unsigned short* Pv = Pr + 2 * CD;

    F4 rm1, r0, rp1, km1, k0, kp1, vm1, v0, vp1;
    rm1 = (t0 > 0) ? ld_bf4(Pr + (size_t)(t0 - 1) * RS) : zero4f();
    r0  = ld_bf4(Pr + (size_t)t0 * RS);
    rp1 = ld_bf4(Pr + (size_t)(t0 + 1) * RS);
    km1 = (t0 > 0) ? ld_bf4(Pk + (size_t)(t0 - 1) * RS) : zero4f();
    k0  = ld_bf4(Pk + (size_t)t0 * RS);
    kp1 = ld_bf4(Pk + (size_t)(t0 + 1) * RS);
    vm1 = (t0 > 0) ? ld_bf4(Pv + (size_t)(t0 - 1) * RS) : zero4f();
    v0  = ld_bf4(Pv + (size_t)t0 * RS);
    vp1 = ld_bf4(Pv + (size_t)(t0 + 1) * RS);

    size_t pbase = ((size_t)n * NCH + ch) * CD + c;
    F4 cE, cEV;
    cE.v  = *(const float4*)(pE + pbase);
    cEV.v = *(const float4*)(pEV + pbase);

    const float omR = 1.f - epsR, omK = 1.f - epsK, omV = 1.f - epsV;
    unsigned short* gbase = gated + ((size_t)n * TT + t0) * CD + c;

#pragma unroll 4
    for (int i = 0; i < CHL; ++i) {
        const int t = t0 + i;
        const float trem = (float)(TT - 1 - t);
        ushort4 og;
        unsigned short* ogp = (unsigned short*)&og;
#pragma unroll
        for (int j = 0; j < 4; j++) {
            float kk = epsK * km1.a[j] + omK * kp1.a[j] + bk4.a[j];
            float vv = epsV * vm1.a[j] + omV * vp1.a[j] + bv4.a[j];
            float rr = epsR * rm1.a[j] + omR * rp1.a[j] + br4.a[j];
            float e  = clip_exp(-w.a[j] * trem + kk);
            float eu = clip_exp(u.a[j] + kk);
            float Aj = cEV.a[j] + eu * vv;
            float Bj = cE.a[j] + eu;
            float wkv = Aj / Bj;
            float sig = 1.f / (1.f + expf(-rr));
            ogp[j] = f2bf(sig * wkv);
            cEV.a[j] += e * vv;
            cE.a[j]  += e;
        }
        *(ushort4*)(gbase + (size_t)i * CD) = og;
        rm1 = r0; r0 = rp1;
        km1 = k0; k0 = kp1;
        vm1 = v0; v0 = vp1;
        if (t + 2 < TT) {
            rp1 = ld_bf4(Pr + (size_t)(t + 2) * RS);
            kp1 = ld_bf4(Pk + (size_t)(t + 2) * RS);
            vp1 = ld_bf4(Pv + (size_t)(t + 2) * RS);
        } else {
            rp1 = zero4f(); kp1 = zero4f(); vp1 = zero4f();
        }
    }
}

// ---------------- launcher ----------------
extern "C" void kernel_launch(void* const* d_in, const int* in_sizes, int n_in,
                              void* d_out, int out_size, void* d_ws, size_t ws_size,
                              hipStream_t stream) {
    const float* x  = (const float*)d_in[0];
    const float* Wr = (const float*)d_in[1];
    const float* br = (const float*)d_in[2];
    const float* Wk = (const float*)d_in[3];
    const float* bk = (const float*)d_in[4];
    const float* Wv = (const float*)d_in[5];
    const float* bv = (const float*)d_in[6];
    const float* Wo = (const float*)d_in[7];
    const float* bo = (const float*)d_in[8];
    const float* td = (const float*)d_in[9];
    const float* U  = (const float*)d_in[10];
    float* out = (float*)d_out;

    // eps constants (host-side, double precision like the reference)
    const double eps0 = std::exp(-1.0 / 12.0);
    const float epsR = (float)(eps0 / 2.0);
    const float epsK = (float)(eps0 + 0.3 * 1.0 / 11.0);
    const float epsV = (float)eps0;

    // workspace carve-up (~74 MB of d_ws)
    char* p = (char*)d_ws;
    auto take = [&](size_t bytes) { char* q = p; p += (bytes + 255) & ~(size_t)255; return q; };
    unsigned short* Wcat_bf = (unsigned short*)take((size_t)NPROJ * CD * 2);  // [Wr;Wk;Wv] bf16
    unsigned short* Wo_bf   = (unsigned short*)take((size_t)CD * CD * 2);
    unsigned short* xbf     = (unsigned short*)take((size_t)MROWS * CD * 2);  // x bf16, later reused as gated
    unsigned short* Pbuf    = (unsigned short*)take((size_t)MROWS * NPROJ * 2); // fused projections bf16
    float*          pE      = (float*)take((size_t)NB * NCH * CD * 4);
    float*          pEV     = (float*)take((size_t)NB * NCH * CD * 4);

    // one fused cast dispatch: 4 weights + x
    const int cast_total = 4 * WQ + XQ;    // 3145728 float4
    cast_all_kernel<<<(cast_total + 255) / 256, 256, 0, stream>>>(Wr, Wk, Wv, Wo, x,
                                                                  Wcat_bf, Wo_bf, xbf);

    // fused R/K/V projection: P = x_bf @ Wcat^T  (bias folded into scan combine), bf16 out
    dim3 g1(MROWS / BM, NPROJ / BN);       // 64 x 24
    gemm_bt<unsigned short><<<g1, 256, 0, stream>>>(xbf, Wcat_bf, nullptr, Pbuf, MROWS, NPROJ, CD);

    scan_partial_kernel<<<NB * NCH, 256, 0, stream>>>(Pbuf, td, bk, bv, epsK, epsV, pE, pEV);
    scan_carry_kernel<<<(NB * CD) / 256, 256, 0, stream>>>(pE, pEV);
    scan_apply_kernel<<<NB * NCH, 256, 0, stream>>>(Pbuf, td, U, br, bk, bv, epsR, epsK, epsV,
                                                    pE, pEV, xbf);

    // output GEMM (fp32 out, required by harness)
    dim3 g2(MROWS / BM, CD / BN);          // 64 x 8
    gemm_bt<float><<<g2, 256, 0, stream>>>(xbf, Wo_bf, bo, out, MROWS, CD, CD);
}